// Round 9
// baseline (1144.823 us; speedup 1.0000x reference)
//
#include <hip/hip_runtime.h>
#include <stdint.h>
#include <stddef.h>

#define BATCH 4096
#define HID   1024
#define EMB   64
#define KDIM  1088
#define NKT   34     // KDIM / 32
#define NSTEP 19
#define NOBS  8

typedef _Float16 f16;
typedef _Float16 half8 __attribute__((ext_vector_type(8)));
typedef float    float4v __attribute__((ext_vector_type(4)));

__device__ __forceinline__ float sigm(float x) { return 1.f / (1.f + __expf(-x)); }
__device__ __forceinline__ float tanh_f(float x) { return 1.f - 2.f / (__expf(2.f * x) + 1.f); }

// ---------------------------------------------------------------------------
// Fragment-major X layout: chunk ((row>>4)*34 + (k>>5))*64 + lane, elem k&7,
// lane = (row&15) + 16*((k>>3)&3)  — exactly the 16x16x32 A-operand.
// ---------------------------------------------------------------------------
__device__ __forceinline__ int xf_idx(int row, int k) {
  return ((((row >> 4) * NKT + (k >> 5)) * 64) + (row & 15) + (((k >> 3) & 3) << 4)) * 8 + (k & 7);
}

// ---------------------------------------------------------------------------
// Pack W_ih|W_hh -> fragment-major fp16 Wsw (B-operand-major, gate-interleaved
// pcols p = 128t+32g+u), + combined bias.
// ---------------------------------------------------------------------------
__global__ void pack_kernel(const float* __restrict__ W_ih, const float* __restrict__ b_ih,
                            const float* __restrict__ W_hh, const float* __restrict__ b_hh,
                            f16* __restrict__ Wsw, float* __restrict__ bc) {
  int gid = blockIdx.x * blockDim.x + threadIdx.x;  // 4096*1088
  int j = gid & 7;
  int lane = (gid >> 3) & 63;
  int c16 = (gid >> 9) & 255;
  int kt = gid >> 17;
  int p = c16 * 16 + (lane & 15);
  int k = kt * 32 + ((lane >> 4) << 3) + j;
  int t = p >> 7, g = (p >> 5) & 3, u = p & 31;
  int orig = g * HID + t * 32 + u;
  float val = (k < EMB) ? W_ih[orig * EMB + k] : W_hh[orig * HID + (k - EMB)];
  Wsw[gid] = (f16)val;
  if (k == 0) bc[p] = b_ih[orig] + b_hh[orig];
}

// ---------------------------------------------------------------------------
__global__ void emb0_kernel(const float* __restrict__ observed,
                            const float* __restrict__ W_emb, const float* __restrict__ b_emb,
                            f16* __restrict__ Xf) {
  int gid = blockIdx.x * blockDim.x + threadIdx.x;  // BATCH*EMB
  int b = gid >> 6, j = gid & 63;
  const float* o0 = observed + b * 2;
  const float* o1 = o0 + BATCH * 2;
  float d0 = o1[0] - o0[0];
  float d1 = o1[1] - o0[1];
  float v = d0 * W_emb[2 * j] + d1 * W_emb[2 * j + 1] + b_emb[j];
  Xf[xf_idx(b, j)] = (f16)fmaxf(v, 0.f);
}

// ---------------------------------------------------------------------------
// Fused gates-GEMM + LSTM cell + out-proj partials. Zero LDS, zero barriers.
// Block: 4 waves x 64 rows (256 rows) x 128 pcols (=32 h-cols).
// c-state fp16. Out-proj partials butterfly-reduced over l15, written per tt.
// ---------------------------------------------------------------------------
__global__ __launch_bounds__(256, 2)
void gemm_cell_kernel(const f16* __restrict__ Xf, const f16* __restrict__ Wsw,
                      const float* __restrict__ bc,
                      f16* __restrict__ c_ws, f16* __restrict__ Xn,
                      float* __restrict__ po_ws, const float* __restrict__ W_out,
                      const float* __restrict__ obs_next, int do_emb,
                      const float* __restrict__ W_emb, const float* __restrict__ b_emb) {
  const int tid = threadIdx.x;
  const int lane = tid & 63;
  const int w = tid >> 6;
  const int l15 = lane & 15;
  const int quad = lane >> 4;
  const int tt = blockIdx.x;            // N tile: 128 pcols = 32 h-cols
  const int mB = blockIdx.y;            // M block: 256 rows
  const int rt0 = mB * 16 + w * 4;      // this wave's first rowtile

  const f16* aB = Xf + (size_t)rt0 * (NKT * 512) + lane * 8;   // +mi*NKT*512 +kt*512
  const f16* bB = Wsw + (size_t)tt * 8 * 512 + lane * 8;       // +ni*512 +kt*131072

  float4v acc[4][8];
#pragma unroll
  for (int mi = 0; mi < 4; ++mi)
#pragma unroll
    for (int ni = 0; ni < 8; ++ni) acc[mi][ni] = (float4v){0.f, 0.f, 0.f, 0.f};

  half8 afA[4], bfA[8], afB[4], bfB[8];

#define LOADF(af, bf, kt)                                                          \
  do {                                                                             \
    _Pragma("unroll") for (int mi = 0; mi < 4; ++mi)                               \
        af[mi] = *(const half8*)(aB + mi * (NKT * 512) + (kt) * 512);              \
    _Pragma("unroll") for (int ni = 0; ni < 8; ++ni)                               \
        bf[ni] = *(const half8*)(bB + ni * 512 + (kt) * 131072);                   \
  } while (0)

#define MFMA_ALL(af, bf)                                                           \
  do {                                                                             \
    _Pragma("unroll") for (int mi = 0; mi < 4; ++mi)                               \
    _Pragma("unroll") for (int ni = 0; ni < 8; ++ni)                               \
        acc[mi][ni] =                                                              \
            __builtin_amdgcn_mfma_f32_16x16x32_f16(af[mi], bf[ni], acc[mi][ni], 0, 0, 0); \
  } while (0)

  LOADF(afA, bfA, 0);
  for (int i = 0; i < NKT / 2; ++i) {
    const int k1 = 2 * i + 1;
    LOADF(afB, bfB, k1);
    MFMA_ALL(afA, bfA);
    if (k1 + 1 < NKT) LOADF(afA, bfA, k1 + 1);
    MFMA_ALL(afB, bfB);
  }
#undef LOADF
#undef MFMA_ALL

  // ---- epilogue: LSTM cell (fp16 c) + out-proj partials ----
  float bias[8];
#pragma unroll
  for (int ni = 0; ni < 8; ++ni) bias[ni] = bc[tt * 128 + ni * 16 + l15];

  float wb[2][5];
#pragma unroll
  for (int u16 = 0; u16 < 2; ++u16)
#pragma unroll
    for (int o = 0; o < 5; ++o)
      wb[u16][o] = W_out[o * HID + tt * 32 + u16 * 16 + l15];

  f16* cbase = c_ws + ((size_t)(mB * 32 + tt) * 256 + tid) * 32;
  half8 cv8[4];
#pragma unroll
  for (int q = 0; q < 4; ++q) cv8[q] = *(const half8*)(cbase + q * 8);

#pragma unroll
  for (int mi = 0; mi < 4; ++mi) {
#pragma unroll
    for (int r = 0; r < 4; ++r) {
      const int row = mB * 256 + w * 64 + mi * 16 + quad * 4 + r;
      float pa[5] = {0.f, 0.f, 0.f, 0.f, 0.f};
#pragma unroll
      for (int u16 = 0; u16 < 2; ++u16) {
        const int j = tt * 32 + u16 * 16 + l15;
        const int ce = (mi * 2 + u16) * 4 + r;  // c element 0..31
        float gi = acc[mi][u16 + 0][r] + bias[u16 + 0];
        float gf = acc[mi][u16 + 2][r] + bias[u16 + 2];
        float gg = acc[mi][u16 + 4][r] + bias[u16 + 4];
        float go = acc[mi][u16 + 6][r] + bias[u16 + 6];
        float co = (float)cv8[ce >> 3][ce & 7];
        float cn = sigm(gf) * co + sigm(gi) * tanh_f(gg);
        cv8[ce >> 3][ce & 7] = (f16)cn;
        float h = sigm(go) * tanh_f(cn);
        Xn[xf_idx(row, EMB + j)] = (f16)h;
#pragma unroll
        for (int o = 0; o < 5; ++o) pa[o] += h * wb[u16][o];
      }
      // butterfly-reduce over l15 (bits 0..3 of lane)
#pragma unroll
      for (int o = 0; o < 5; ++o) {
        pa[o] += __shfl_xor(pa[o], 1, 64);
        pa[o] += __shfl_xor(pa[o], 2, 64);
        pa[o] += __shfl_xor(pa[o], 4, 64);
        pa[o] += __shfl_xor(pa[o], 8, 64);
      }
      if (l15 == 0) {
        float* pdst = po_ws + ((size_t)tt * BATCH + row) * 5;
#pragma unroll
        for (int o = 0; o < 5; ++o) pdst[o] = pa[o];
      }
    }
  }
#pragma unroll
  for (int q = 0; q < 4; ++q) *(half8*)(cbase + q * 8) = cv8[q];

  // ---- fused obs-emb for step t+1 (tt==0 blocks, vectorized half8) ----
  if (do_emb && tt == 0) {
    const int row = mB * 256 + tid;
    const float* o0 = obs_next + row * 2;
    const float* o1 = o0 + BATCH * 2;
    float d0 = o1[0] - o0[0];
    float d1 = o1[1] - o0[1];
    const int rt = row >> 4;
#pragma unroll
    for (int kt = 0; kt < 2; ++kt)
#pragma unroll
      for (int kl = 0; kl < 4; ++kl) {
        half8 hv;
#pragma unroll
        for (int e = 0; e < 8; ++e) {
          int j = kt * 32 + kl * 8 + e;
          float v = d0 * W_emb[2 * j] + d1 * W_emb[2 * j + 1] + b_emb[j];
          hv[e] = (f16)fmaxf(v, 0.f);
        }
        *(half8*)(Xn + (((rt * NKT + kt) * 64) + (row & 15) + 16 * kl) * 8) = hv;
      }
  }
}

// ---------------------------------------------------------------------------
// Reduce out-proj partials over 32 tt slices, add bias, write out;
// optionally compute pred-emb for t+1 into Xn. 128 blocks x 256 thr,
// 32 rows per block.
// ---------------------------------------------------------------------------
__global__ __launch_bounds__(256)
void reduce_kernel(const float* __restrict__ po_ws, const float* __restrict__ b_out,
                   float* __restrict__ out_t, int emb_flag,
                   const float* __restrict__ W_emb, const float* __restrict__ b_emb,
                   f16* __restrict__ Xn) {
  __shared__ float s_nv[32][2];
  const int tid = threadIdx.x;
  const int r0 = blockIdx.x * 32;

  if (tid < 160) {
    const int rowl = tid / 5, o = tid - rowl * 5;
    const int row = r0 + rowl;
    float s = 0.f;
#pragma unroll
    for (int tt = 0; tt < 32; ++tt) s += po_ws[((size_t)tt * BATCH + row) * 5 + o];
    float v = s + b_out[o];
    out_t[(size_t)row * 5 + o] = v;
    if (o < 2) s_nv[rowl][o] = v;
  }
  if (emb_flag) {
    __syncthreads();
    const int rowl = tid >> 3, kt = (tid >> 2) & 1, kl = tid & 3;
    const int row = r0 + rowl;
    const float d0 = s_nv[rowl][0], d1 = s_nv[rowl][1];
    half8 hv;
#pragma unroll
    for (int e = 0; e < 8; ++e) {
      int j = kt * 32 + kl * 8 + e;
      float v = d0 * W_emb[2 * j] + d1 * W_emb[2 * j + 1] + b_emb[j];
      hv[e] = (f16)fmaxf(v, 0.f);
    }
    *(half8*)(Xn + ((((row >> 4) * NKT + kt) * 64) + (row & 15) + 16 * kl) * 8) = hv;
  }
}

// ---------------------------------------------------------------------------
extern "C" void kernel_launch(void* const* d_in, const int* in_sizes, int n_in,
                              void* d_out, int out_size, void* d_ws, size_t ws_size,
                              hipStream_t stream) {
  const float* observed = (const float*)d_in[0];
  const float* W_emb = (const float*)d_in[1];
  const float* b_emb = (const float*)d_in[2];
  const float* W_ih = (const float*)d_in[3];
  const float* b_ih = (const float*)d_in[4];
  const float* W_hh = (const float*)d_in[5];
  const float* b_hh = (const float*)d_in[6];
  const float* W_out = (const float*)d_in[7];
  const float* b_out = (const float*)d_in[8];
  float* out = (float*)d_out;

  uint8_t* ws = (uint8_t*)d_ws;
  const size_t WC_BYTES = (size_t)4096 * KDIM * sizeof(f16);  // 8,912,896
  f16* Wsw = (f16*)ws;
  float* bc = (float*)(ws + WC_BYTES);
  f16* X0 = (f16*)(ws + WC_BYTES + 16384);
  f16* X1 = (f16*)(ws + 2 * WC_BYTES + 16384);
  f16* c_ws = (f16*)(ws + 3 * WC_BYTES + 16384);
  float* po_ws = (float*)(ws + 3 * WC_BYTES + 16384 + (size_t)BATCH * HID * 2);

  pack_kernel<<<(4096 * KDIM) / 256, 256, 0, stream>>>(W_ih, b_ih, W_hh, b_hh, Wsw, bc);
  hipMemsetAsync(X0, 0, WC_BYTES, stream);                   // h0 = 0 (emb cols below)
  hipMemsetAsync(c_ws, 0, (size_t)BATCH * HID * 2, stream);  // c0 = 0
  emb0_kernel<<<(BATCH * EMB) / 256, 256, 0, stream>>>(observed, W_emb, b_emb, X0);

  for (int t = 0; t < NSTEP; ++t) {
    f16* Xc = (t & 1) ? X1 : X0;
    f16* Xn = (t & 1) ? X0 : X1;
    const int do_emb = (t + 1 < NOBS) ? 1 : 0;
    dim3 grid(32, 16);  // x: N tiles (128 pcols), y: M blocks (256 rows)
    gemm_cell_kernel<<<grid, 256, 0, stream>>>(
        Xc, Wsw, bc, c_ws, Xn, po_ws, W_out,
        observed + (size_t)(t + 1) * BATCH * 2, do_emb, W_emb, b_emb);
    const int emb_pred = (t >= 7 && t + 1 < NSTEP) ? 1 : 0;
    reduce_kernel<<<BATCH / 32, 256, 0, stream>>>(
        po_ws, b_out, out + (size_t)t * BATCH * 5, emb_pred, W_emb, b_emb, Xn);
  }
}